// Round 15
// baseline (350.699 us; speedup 1.0000x reference)
//
#include <hip/hip_runtime.h>
#include <math.h>

#define NPIX 4096
#define CCH 256

typedef __attribute__((ext_vector_type(4))) float f32x4;
typedef __attribute__((ext_vector_type(16))) float f32x16;
typedef __attribute__((ext_vector_type(8))) short s16x8;
typedef unsigned short u16;

__device__ __forceinline__ short bf16_rne(float x) {
  union { float f; unsigned u; } c; c.f = x;
  unsigned r = c.u + 0x7FFF + ((c.u >> 16) & 1);
  return (short)(r >> 16);
}
__device__ __forceinline__ unsigned cvtpk2(float lo, float hi) {
  unsigned r;
  asm("v_cvt_pk_bf16_f32 %0, %1, %2" : "=v"(r) : "v"(lo), "v"(hi));
  return r;
}
__device__ __forceinline__ unsigned pack2(float a, float b) {
  return cvtpk2(a, b);
}
__device__ __forceinline__ float max3f(float a, float b, float c) {
  float d;
  asm("v_max3_f32 %0, %1, %2, %3" : "=v"(d) : "v"(a), "v"(b), "v"(c));
  return d;
}
__device__ __forceinline__ float bf16_to_f32(unsigned short v) {
  return __uint_as_float(((unsigned)v) << 16);
}

// permlane32_swap via builtin (compiler-managed hazards — R2 lesson).
// TRUE semantics (R7 lesson): swap(a,b) -> a' = [a.lo, b.lo], b' = [a.hi, b.hi]
__device__ __forceinline__ void plane32_swap(unsigned& a, unsigned& b) {
#if __has_builtin(__builtin_amdgcn_permlane32_swap)
  auto r = __builtin_amdgcn_permlane32_swap(a, b, false, false);
  a = r[0]; b = r[1];
#else
  asm("s_nop 2\n\tv_permlane32_swap_b32 %0, %1\n\ts_nop 2" : "+v"(a), "+v"(b));
#endif
}
// cross-half (lane l <-> l+32) reductions, VALU pipe only
__device__ __forceinline__ float red_max_half(float x) {
  unsigned a = __float_as_uint(x), b = a;
  plane32_swap(a, b);
  return fmaxf(__uint_as_float(a), __uint_as_float(b));
}
__device__ __forceinline__ float red_sum_half(float x) {
  unsigned a = __float_as_uint(x), b = a;
  plane32_swap(a, b);
  return __uint_as_float(a) + __uint_as_float(b);
}

#define QSCALE 0.18033688011f   /* 0.125 * log2(e) */

// ---------------- GN partial stats + weight/bias convert (fused): 256 blocks ----------------
__global__ __launch_bounds__(256) void gn_stats_wcvt(
    const float* __restrict__ x, const float* __restrict__ qkv_w, const float* __restrict__ proj_w,
    const float* __restrict__ qkv_b, double2* __restrict__ partials,
    u16* __restrict__ wq, u16* __restrict__ wp, float* __restrict__ biasq)
{
  const int blk = blockIdx.x, tid = threadIdx.x;
  // weight convert: 1024 entries per block (256 blocks x 1024 = 262144)
#pragma unroll
  for (int p = 0; p < 4; ++p) {
    int idx = blk * 1024 + p * 256 + tid;
    if (idx < 196608) {
      float v = qkv_w[idx];
      if (idx < 65536) v *= QSCALE;             // q rows pre-scaled
      wq[idx] = (u16)bf16_rne(v);
    } else {
      int j = idx - 196608;
      wp[j] = (u16)bf16_rne(proj_w[j]);
    }
    if (idx < 768) {
      float bv = qkv_b[idx];
      if (idx < 256) bv *= QSCALE;
      biasq[idx] = bv;
    }
  }
  // stats partial for chunk
  const int bg = blk >> 3, chunk = blk & 7;
  const float4* base = (const float4*)(x + (size_t)bg * 131072 + (size_t)chunk * 16384);
  double s = 0.0, ss = 0.0;
  for (int idx = tid; idx < 4096; idx += 256) {
    float4 v = base[idx];
    s  += (double)v.x + (double)v.y + (double)v.z + (double)v.w;
    ss += (double)v.x * v.x + (double)v.y * v.y + (double)v.z * v.z + (double)v.w * v.w;
  }
  __shared__ double rs[256], rss[256];
  rs[tid] = s; rss[tid] = ss;
  __syncthreads();
  for (int off = 128; off > 0; off >>= 1) {
    if (tid < off) { rs[tid] += rs[tid + off]; rss[tid] += rss[tid + off]; }
    __syncthreads();
  }
  if (tid == 0) {
    double2 p; p.x = rs[0]; p.y = rss[0];
    partials[blk] = p;
  }
}

// ---------------- GN apply + transpose (self-finalizing alpha/beta) ----------------
__global__ __launch_bounds__(256) void gn_apply_t2(
    const float* __restrict__ x, const double2* __restrict__ partials,
    const float* __restrict__ gn_w, const float* __restrict__ gn_b,
    u16* __restrict__ Xt)
{
  const int b = blockIdx.z, c0 = blockIdx.y * 64, n0 = blockIdx.x * 64;
  const int tid = threadIdx.x;
  __shared__ u16 T[64 * 68];
  __shared__ float sal[64], sbe[64], smv[2], srv[2];
  if (tid < 2) {
    int bg = b * 8 + (c0 >> 5) + tid;
    double s = 0.0, ss = 0.0;
    for (int c = 0; c < 8; ++c) { double2 p = partials[bg * 8 + c]; s += p.x; ss += p.y; }
    double mean = s / 131072.0;
    double var  = ss / 131072.0 - mean * mean;
    smv[tid] = (float)mean;
    srv[tid] = (float)(1.0 / sqrt(var + 1e-5));
  }
  __syncthreads();
  if (tid < 64) {
    int g = tid >> 5;
    int ch = c0 + tid;
    float a = srv[g] * gn_w[ch];
    sal[tid] = a;
    sbe[tid] = gn_b[ch] - smv[g] * a;
  }
  __syncthreads();
  const int n4 = (tid & 15) * 4, cr = tid >> 4;
#pragma unroll
  for (int p = 0; p < 4; ++p) {
    int cl = cr + 16 * p;
    int c = c0 + cl;
    float a = sal[cl], bt = sbe[cl];
    float4 v = *(const float4*)&x[((size_t)b * CCH + c) * NPIX + n0 + n4];
    T[(n4 + 0) * 68 + cl] = (u16)bf16_rne(v.x * a + bt);
    T[(n4 + 1) * 68 + cl] = (u16)bf16_rne(v.y * a + bt);
    T[(n4 + 2) * 68 + cl] = (u16)bf16_rne(v.z * a + bt);
    T[(n4 + 3) * 68 + cl] = (u16)bf16_rne(v.w * a + bt);
  }
  __syncthreads();
#pragma unroll
  for (int it = 0; it < 2; ++it) {
    int linear = it * 256 + tid;
    int n = linear >> 3, ch = linear & 7;
    s16x8 v = *(const s16x8*)&T[n * 68 + ch * 8];
    *(s16x8*)&Xt[((size_t)b * NPIX + n0 + n) * CCH + c0 + ch * 8] = v;
  }
}

// ---------------- QKV GEMM v1 (R9-verified): D[m][n] = W[m][k] Xt[n][k] + bias ----------------
__global__ __launch_bounds__(256) void qkv_gemm_kernel(
    const u16* __restrict__ Wbf, const float* __restrict__ biasv, const u16* __restrict__ Xt,
    u16* __restrict__ Qt, u16* __restrict__ Kt, u16* __restrict__ Vb)
{
  const int nblk = blockIdx.x, m0 = blockIdx.y * 64;
  const int tid = threadIdx.x, wave = tid >> 6, lane = tid & 63;
  const int n16 = lane & 15, quad = lane >> 4;
  const int n0 = nblk * 128 + wave * 32;   // flat row (b*4096 + i)

  f32x4 acc[4][2];
#pragma unroll
  for (int a = 0; a < 4; ++a)
#pragma unroll
    for (int c = 0; c < 2; ++c) acc[a][c] = (f32x4){0.f, 0.f, 0.f, 0.f};

#pragma unroll
  for (int k0 = 0; k0 < 256; k0 += 32) {
    s16x8 af[4], bfr[2];
#pragma unroll
    for (int msub = 0; msub < 4; ++msub)
      af[msub] = *(const s16x8*)&Wbf[(size_t)(m0 + msub * 16 + n16) * 256 + k0 + quad * 8];
#pragma unroll
    for (int nsub = 0; nsub < 2; ++nsub)
      bfr[nsub] = *(const s16x8*)&Xt[(size_t)(n0 + nsub * 16 + n16) * 256 + k0 + quad * 8];
#pragma unroll
    for (int msub = 0; msub < 4; ++msub)
#pragma unroll
      for (int nsub = 0; nsub < 2; ++nsub)
        acc[msub][nsub] = __builtin_amdgcn_mfma_f32_16x16x32_bf16(af[msub], bfr[nsub], acc[msub][nsub], 0, 0, 0);
  }

  __shared__ u16 T[8704];   // qk: [n128][m 68]; v: [m64][n 136]
  if (m0 < 512) {
    // bias + pack, store transposed tile [n][m]
#pragma unroll
    for (int msub = 0; msub < 4; ++msub)
#pragma unroll
      for (int nsub = 0; nsub < 2; ++nsub) {
        float b0 = biasv[m0 + msub * 16 + quad * 4 + 0];
        float b1 = biasv[m0 + msub * 16 + quad * 4 + 1];
        float b2 = biasv[m0 + msub * 16 + quad * 4 + 2];
        float b3 = biasv[m0 + msub * 16 + quad * 4 + 3];
        uint2 w2;
        w2.x = pack2(acc[msub][nsub][0] + b0, acc[msub][nsub][1] + b1);
        w2.y = pack2(acc[msub][nsub][2] + b2, acc[msub][nsub][3] + b3);
        *(uint2*)&T[(wave * 32 + nsub * 16 + n16) * 68 + msub * 16 + quad * 4] = w2;
      }
    __syncthreads();
    u16* dst = (m0 < 256) ? Qt : Kt;
    const int coff = m0 & 255;
#pragma unroll
    for (int it = 0; it < 4; ++it) {
      int linear = it * 256 + tid;
      int n = linear >> 3, ch = linear & 7;
      s16x8 v = *(const s16x8*)&T[n * 68 + ch * 8];
      *(s16x8*)&dst[(size_t)(nblk * 128 + n) * 256 + coff + ch * 8] = v;
    }
  } else {
    // V: store [m][n] natural rows
#pragma unroll
    for (int msub = 0; msub < 4; ++msub)
#pragma unroll
      for (int nsub = 0; nsub < 2; ++nsub) {
        int ncol = wave * 32 + nsub * 16 + n16;
#pragma unroll
        for (int r = 0; r < 4; ++r) {
          int m = msub * 16 + quad * 4 + r;
          T[m * 136 + ncol] = (u16)bf16_rne(acc[msub][nsub][r] + biasv[m0 + m]);
        }
      }
    __syncthreads();
    const int b = (nblk * 128) >> 12, i0n = (nblk * 128) & 4095;
#pragma unroll
    for (int it = 0; it < 4; ++it) {
      int linear = it * 256 + tid;
      int mloc = linear >> 4, ch = linear & 15;
      s16x8 v = *(const s16x8*)&T[mloc * 136 + ch * 8];
      int c = (m0 - 512) + mloc;
      *(s16x8*)&Vb[((size_t)b * CCH + c) * NPIX + i0n + ch * 8] = v;
    }
  }
}

// ---------------- MFMA flash attention v6c: v6b + V-frag preload (T14-lite) ----------------
// No swizzle (T1 reverted: R14 showed FETCH -73% but dur +8us). V fragments are
// read from LDS into registers right after QK MFMAs so the ~500cy softmax VALU
// chain hides their ds_read latency; PV MFMAs then issue back-to-back.
__device__ __forceinline__ void kv_load6(
    const u16* __restrict__ Kb, const u16* __restrict__ Vg, int h, int j0, int sj, int part,
    s16x8& k0, s16x8& k1, s16x8& v0, s16x8& v1)
{
  const s16x8* kp = (const s16x8*)&Kb[(size_t)(j0 + sj) * 256 + h * 64 + part * 16];
  const s16x8* vp = (const s16x8*)&Vg[(size_t)sj * NPIX + j0 + part * 16];
  k0 = kp[0]; k1 = kp[1]; v0 = vp[0]; v1 = vp[1];
}
__device__ __forceinline__ void kv_store6(
    u16* Ksb, u16* Vsb, int sbase,
    s16x8 k0, s16x8 k1, s16x8 v0, s16x8 v1)
{
  *(s16x8*)&Ksb[sbase]       = k0;
  *(s16x8*)&Ksb[sbase + 256] = k1;
  *(s16x8*)&Vsb[sbase]       = v0;
  *(s16x8*)&Vsb[sbase + 256] = v1;
}

__device__ __forceinline__ void attn_tile6(
    const u16* Ksb, const u16* Vsb, const s16x8 qf[4], int lane,
    f32x16 ot[2], float& m_i, float& l_i)
{
  f32x16 st[2];
#pragma unroll
  for (int r = 0; r < 16; ++r) { st[0][r] = 0.f; st[1][r] = 0.f; }

  __builtin_amdgcn_s_setprio(1);
#pragma unroll
  for (int kq = 0; kq < 4; ++kq)
#pragma unroll
    for (int jsub = 0; jsub < 2; ++jsub) {
      s16x8 a = *(const s16x8*)&Ksb[(jsub * 4 + kq) * 512 + lane * 8];
      st[jsub] = __builtin_amdgcn_mfma_f32_32x32x16_bf16(a, qf[kq], st[jsub], 0, 0, 0);
    }
  __builtin_amdgcn_s_setprio(0);

  // V-frag preload (T14-lite): issue all 8 ds_reads now; softmax hides latency.
  s16x8 vf[8];
#pragma unroll
  for (int f = 0; f < 8; ++f)
    vf[f] = *(const s16x8*)&Vsb[f * 512 + lane * 8];

  float c0 = max3f(st[0][0],  st[0][1],  st[0][2]);
  float c1 = max3f(st[0][3],  st[0][4],  st[0][5]);
  float c2 = max3f(st[0][6],  st[0][7],  st[0][8]);
  float c3 = max3f(st[0][9],  st[0][10], st[0][11]);
  float c4 = max3f(st[0][12], st[0][13], st[0][14]);
  float c5 = max3f(st[0][15], st[1][0],  st[1][1]);
  float c6 = max3f(st[1][2],  st[1][3],  st[1][4]);
  float c7 = max3f(st[1][5],  st[1][6],  st[1][7]);
  float c8 = max3f(st[1][8],  st[1][9],  st[1][10]);
  float c9 = max3f(st[1][11], st[1][12], st[1][13]);
  float d0 = max3f(c0, c1, c2);
  float d1 = max3f(c3, c4, c5);
  float d2 = max3f(c6, c7, c8);
  float d3 = max3f(c9, st[1][14], st[1][15]);
  float tm = fmaxf(fmaxf(d0, d1), fmaxf(d2, d3));
  tm = red_max_half(tm);

  if (__any(tm > m_i + 8.0f)) {
    float mn = fmaxf(m_i, tm);
    float al = __builtin_amdgcn_exp2f(m_i - mn);
    m_i = mn;
    l_i *= al;
#pragma unroll
    for (int r = 0; r < 16; ++r) { ot[0][r] *= al; ot[1][r] *= al; }
  }

#pragma unroll
  for (int f = 0; f < 2; ++f)
#pragma unroll
    for (int r = 0; r < 16; ++r)
      st[f][r] = __builtin_amdgcn_exp2f(st[f][r] - m_i);

  float s0 = (st[0][0] + st[0][1]) + (st[0][2]  + st[0][3]);
  float s1 = (st[0][4] + st[0][5]) + (st[0][6]  + st[0][7]);
  float s2 = (st[0][8] + st[0][9]) + (st[0][10] + st[0][11]);
  float s3 = (st[0][12]+ st[0][13])+ (st[0][14] + st[0][15]);
  float s4 = (st[1][0] + st[1][1]) + (st[1][2]  + st[1][3]);
  float s5 = (st[1][4] + st[1][5]) + (st[1][6]  + st[1][7]);
  float s6 = (st[1][8] + st[1][9]) + (st[1][10] + st[1][11]);
  float s7 = (st[1][12]+ st[1][13])+ (st[1][14] + st[1][15]);
  float ps = ((s0 + s1) + (s2 + s3)) + ((s4 + s5) + (s6 + s7));
  ps = red_sum_half(ps);
  l_i += ps;

  // P^T -> PV B-frags (R8-verified routing): swap(u0,u2); swap(u1,u3)
#pragma unroll
  for (int jq = 0; jq < 4; ++jq) {
    const int jsub = jq >> 1;
    const int b0 = (jq & 1) * 8;
    const int b1 = b0 + 4;
    unsigned u0 = cvtpk2(st[jsub][b0 + 0], st[jsub][b0 + 1]);
    unsigned u1 = cvtpk2(st[jsub][b0 + 2], st[jsub][b0 + 3]);
    unsigned u2 = cvtpk2(st[jsub][b1 + 0], st[jsub][b1 + 1]);
    unsigned u3 = cvtpk2(st[jsub][b1 + 2], st[jsub][b1 + 3]);
    plane32_swap(u0, u2);
    plane32_swap(u1, u3);
    union { unsigned u[4]; s16x8 v; } pu;
    pu.u[0] = u0; pu.u[1] = u1; pu.u[2] = u2; pu.u[3] = u3;
    __builtin_amdgcn_s_setprio(1);
#pragma unroll
    for (int dsub = 0; dsub < 2; ++dsub)
      ot[dsub] = __builtin_amdgcn_mfma_f32_32x32x16_bf16(vf[dsub * 4 + jq], pu.v, ot[dsub], 0, 0, 0);
    __builtin_amdgcn_s_setprio(0);
  }
}

__global__ __launch_bounds__(256, 4) void attn_kernel6(
    const u16* __restrict__ Qt, const u16* __restrict__ Kt,
    const u16* __restrict__ Vb, u16* __restrict__ P0, u16* __restrict__ P1,
    float* __restrict__ mlbuf)
{
  const int b = blockIdx.z, h = blockIdx.y;
  const int xb = blockIdx.x;
  const int half = xb >> 5, iblk = xb & 31;
  const int tid = threadIdx.x;
  const int wave = tid >> 6, lane = tid & 63;
  const int i0w = iblk * 128 + wave * 32;

  __shared__ u16 Ks[2][4096];
  __shared__ u16 Vs[2][4096];

  const u16* Qb = Qt + (size_t)b * NPIX * 256;
  const u16* Kb = Kt + (size_t)b * NPIX * 256;
  const u16* Vg = Vb + ((size_t)b * CCH + h * 64) * NPIX;

  s16x8 qf[4];
#pragma unroll
  for (int kq = 0; kq < 4; ++kq)
    qf[kq] = *(const s16x8*)&Qb[(size_t)(i0w + (lane & 31)) * 256 + h * 64 + kq * 16 + (lane >> 5) * 8];

  f32x16 ot[2];
#pragma unroll
  for (int r = 0; r < 16; ++r) { ot[0][r] = 0.f; ot[1][r] = 0.f; }
  float m_i = -1e30f;
  float l_i = 0.f;

  const int sj = tid >> 2;
  const int part = tid & 3;
  const int sbase = ((sj >> 5) * 4 + part) * 512 + (sj & 31) * 8;
  const int jbase = half * 2048;

  s16x8 k0, k1, v0, v1;

  kv_load6(Kb, Vg, h, jbase, sj, part, k0, k1, v0, v1);
  kv_store6(Ks[0], Vs[0], sbase, k0, k1, v0, v1);
  __syncthreads();

#pragma unroll 1
  for (int t = 0; t < 30; t += 2) {
    kv_load6(Kb, Vg, h, jbase + (t + 1) * 64, sj, part, k0, k1, v0, v1);
    attn_tile6(Ks[0], Vs[0], qf, lane, ot, m_i, l_i);
    kv_store6(Ks[1], Vs[1], sbase, k0, k1, v0, v1);
    __syncthreads();
    kv_load6(Kb, Vg, h, jbase + (t + 2) * 64, sj, part, k0, k1, v0, v1);
    attn_tile6(Ks[1], Vs[1], qf, lane, ot, m_i, l_i);
    kv_store6(Ks[0], Vs[0], sbase, k0, k1, v0, v1);
    __syncthreads();
  }
  kv_load6(Kb, Vg, h, jbase + 31 * 64, sj, part, k0, k1, v0, v1);
  attn_tile6(Ks[0], Vs[0], qf, lane, ot, m_i, l_i);
  kv_store6(Ks[1], Vs[1], sbase, k0, k1, v0, v1);
  __syncthreads();
  attn_tile6(Ks[1], Vs[1], qf, lane, ot, m_i, l_i);

  float rl = 1.0f / l_i;
  u16* dst = (half == 0) ? P0 : P1;
  const size_t rowbase = (size_t)((size_t)b * NPIX + i0w + (lane & 31)) * 256 + h * 64 + (lane >> 5) * 4;
#pragma unroll
  for (int dsub = 0; dsub < 2; ++dsub)
#pragma unroll
    for (int q = 0; q < 4; ++q) {
      uint2 w2;
      w2.x = cvtpk2(ot[dsub][4 * q + 0] * rl, ot[dsub][4 * q + 1] * rl);
      w2.y = cvtpk2(ot[dsub][4 * q + 2] * rl, ot[dsub][4 * q + 3] * rl);
      *(uint2*)&dst[rowbase + dsub * 32 + q * 8] = w2;
    }
  if (lane < 32) {
    int idx = half * 65536 + b * 16384 + h * 4096 + i0w + lane;
    float2 ml; ml.x = m_i; ml.y = l_i;
    *(float2*)&mlbuf[idx * 2] = ml;
  }
}

// ---------------- Proj GEMM v1 + fused split-KV combine ----------------
__global__ __launch_bounds__(256) void proj_gemm_cmb(
    const u16* __restrict__ Wp, const float* __restrict__ proj_b,
    const u16* __restrict__ P0, const u16* __restrict__ P1, const float* __restrict__ mlbuf,
    const float* __restrict__ x, float* __restrict__ out)
{
  const int nblk = blockIdx.x, m0 = blockIdx.y * 64;
  const int tid = threadIdx.x, wave = tid >> 6, lane = tid & 63;
  const int n16 = lane & 15, quad = lane >> 4;
  const int n0 = nblk * 128 + wave * 32;

  // combine weights for this thread's 2 rows x 4 heads
  float w0h[2][4], w1h[2][4];
#pragma unroll
  for (int ns = 0; ns < 2; ++ns) {
    int row = n0 + ns * 16 + n16;
    int bb = row >> 12, ii = row & 4095;
#pragma unroll
    for (int h = 0; h < 4; ++h) {
      int idx = bb * 16384 + h * 4096 + ii;
      float2 ml0 = *(const float2*)&mlbuf[(size_t)idx * 2];
      float2 ml1 = *(const float2*)&mlbuf[(size_t)(65536 + idx) * 2];
      float m = fmaxf(ml0.x, ml1.x);
      float cc0 = ml0.y * __builtin_amdgcn_exp2f(ml0.x - m);
      float cc1 = ml1.y * __builtin_amdgcn_exp2f(ml1.x - m);
      float rn = 1.0f / (cc0 + cc1);
      w0h[ns][h] = cc0 * rn;
      w1h[ns][h] = cc1 * rn;
    }
  }

  f32x4 acc[4][2];
#pragma unroll
  for (int a = 0; a < 4; ++a)
#pragma unroll
    for (int c = 0; c < 2; ++c) acc[a][c] = (f32x4){0.f, 0.f, 0.f, 0.f};

#pragma unroll
  for (int k0 = 0; k0 < 256; k0 += 32) {
    const int h = k0 >> 6;            // compile-time per unrolled iter
    s16x8 af[4], bfr[2];
#pragma unroll
    for (int msub = 0; msub < 4; ++msub)
      af[msub] = *(const s16x8*)&Wp[(size_t)(m0 + msub * 16 + n16) * 256 + k0 + quad * 8];
#pragma unroll
    for (int nsub = 0; nsub < 2; ++nsub) {
      int row = n0 + nsub * 16 + n16;
      size_t off = (size_t)row * 256 + k0 + quad * 8;
      s16x8 a = *(const s16x8*)&P0[off];
      s16x8 c = *(const s16x8*)&P1[off];
      float w0 = w0h[nsub][h], w1 = w1h[nsub][h];
      union { unsigned u[4]; s16x8 v; } o;
#pragma unroll
      for (int e = 0; e < 4; ++e) {
        float lo = w0 * bf16_to_f32((unsigned short)a[2 * e])     + w1 * bf16_to_f32((unsigned short)c[2 * e]);
        float hi = w0 * bf16_to_f32((unsigned short)a[2 * e + 1]) + w1 * bf16_to_f32((unsigned short)c[2 * e + 1]);
        o.u[e] = cvtpk2(lo, hi);
      }
      bfr[nsub] = o.v;
    }
#pragma unroll
    for (int msub = 0; msub < 4; ++msub)
#pragma unroll
      for (int nsub = 0; nsub < 2; ++nsub)
        acc[msub][nsub] = __builtin_amdgcn_mfma_f32_16x16x32_bf16(af[msub], bfr[nsub], acc[msub][nsub], 0, 0, 0);
  }

  __shared__ float T[64 * 132];
#pragma unroll
  for (int msub = 0; msub < 4; ++msub)
#pragma unroll
    for (int nsub = 0; nsub < 2; ++nsub) {
      int ncol = wave * 32 + nsub * 16 + n16;
#pragma unroll
      for (int r = 0; r < 4; ++r) {
        int m = msub * 16 + quad * 4 + r;
        T[m * 132 + ncol] = acc[msub][nsub][r];
      }
    }
  __syncthreads();
  const int b = (nblk * 128) >> 12, i0n = (nblk * 128) & 4095;
#pragma unroll
  for (int it = 0; it < 8; ++it) {
    int linear = it * 256 + tid;
    int m = linear >> 5, ch = linear & 31;
    f32x4 v = *(const f32x4*)&T[m * 132 + ch * 4];
    float bs = proj_b[m0 + m];
    size_t g = ((size_t)b * CCH + m0 + m) * NPIX + i0n + ch * 4;
    float4 rv = *(const float4*)&x[g];
    float4 o;
    o.x = v[0] + bs + rv.x; o.y = v[1] + bs + rv.y;
    o.z = v[2] + bs + rv.z; o.w = v[3] + bs + rv.w;
    *(float4*)&out[g] = o;
  }
}

extern "C" void kernel_launch(void* const* d_in, const int* in_sizes, int n_in,
                              void* d_out, int out_size, void* d_ws, size_t ws_size,
                              hipStream_t stream)
{
  const float* x      = (const float*)d_in[0];
  const float* gn_w   = (const float*)d_in[1];
  const float* gn_b   = (const float*)d_in[2];
  const float* qkv_w  = (const float*)d_in[3];
  const float* qkv_b  = (const float*)d_in[4];
  const float* proj_w = (const float*)d_in[5];
  const float* proj_b = (const float*)d_in[6];
  float* out = (float*)d_out;

  float* ws    = (float*)d_ws;
  float* biasq = ws + 2048;                // 768
  double2* partials = (double2*)(ws + 2816); // 256 double2 -> ends 3840
  u16*   wq    = (u16*)(ws + 4096);        // 196608 shorts
  u16*   wp    = (u16*)(ws + 102400);      // 65536 shorts
  u16*   Xt    = (u16*)(ws + 135168);      // 4*4096*256 shorts = 2097152 floats
  u16*   Qt    = (u16*)(ws + 2232320);
  u16*   Kt    = (u16*)(ws + 4329472);
  u16*   Vb    = (u16*)(ws + 6426624);
  u16*   Ot    = (u16*)(ws + 8523776);     // ends 10620928 (holds P1)
  float* mlbuf = ws + 10620928;            // 2*65536*2 floats -> ends 10883072 (~43.5 MB)

  // P0 (half-0 partial O) overlays Xt (dead after qkv_gemm); P1 = Ot region.
  u16* P0 = Xt;

  gn_stats_wcvt<<<256, 256, 0, stream>>>(x, qkv_w, proj_w, qkv_b, partials, wq, wp, biasq);
  gn_apply_t2<<<dim3(64, 4, 4), 256, 0, stream>>>(x, partials, gn_w, gn_b, Xt);
  qkv_gemm_kernel<<<dim3(128, 12), 256, 0, stream>>>(wq, biasq, Xt, Qt, Kt, Vb);
  attn_kernel6<<<dim3(64, 4, 4), 256, 0, stream>>>(Qt, Kt, Vb, P0, Ot, mlbuf);
  proj_gemm_cmb<<<dim3(128, 4), 256, 0, stream>>>(wp, proj_b, P0, Ot, mlbuf, x, out);
}

// Round 16
// 241.352 us; speedup vs baseline: 1.4531x; 1.4531x over previous
//
#include <hip/hip_runtime.h>
#include <math.h>

#define NPIX 4096
#define CCH 256

typedef __attribute__((ext_vector_type(4))) float f32x4;
typedef __attribute__((ext_vector_type(16))) float f32x16;
typedef __attribute__((ext_vector_type(8))) short s16x8;
typedef unsigned short u16;

__device__ __forceinline__ short bf16_rne(float x) {
  union { float f; unsigned u; } c; c.f = x;
  unsigned r = c.u + 0x7FFF + ((c.u >> 16) & 1);
  return (short)(r >> 16);
}
__device__ __forceinline__ unsigned cvtpk2(float lo, float hi) {
  unsigned r;
  asm("v_cvt_pk_bf16_f32 %0, %1, %2" : "=v"(r) : "v"(lo), "v"(hi));
  return r;
}
__device__ __forceinline__ unsigned pack2(float a, float b) {
  return cvtpk2(a, b);
}
__device__ __forceinline__ float max3f(float a, float b, float c) {
  float d;
  asm("v_max3_f32 %0, %1, %2, %3" : "=v"(d) : "v"(a), "v"(b), "v"(c));
  return d;
}
__device__ __forceinline__ float bf16_to_f32(unsigned short v) {
  return __uint_as_float(((unsigned)v) << 16);
}

// permlane32_swap via builtin (compiler-managed hazards — R2 lesson).
// TRUE semantics (R7 lesson): swap(a,b) -> a' = [a.lo, b.lo], b' = [a.hi, b.hi]
__device__ __forceinline__ void plane32_swap(unsigned& a, unsigned& b) {
#if __has_builtin(__builtin_amdgcn_permlane32_swap)
  auto r = __builtin_amdgcn_permlane32_swap(a, b, false, false);
  a = r[0]; b = r[1];
#else
  asm("s_nop 2\n\tv_permlane32_swap_b32 %0, %1\n\ts_nop 2" : "+v"(a), "+v"(b));
#endif
}
// cross-half (lane l <-> l+32) reductions, VALU pipe only
__device__ __forceinline__ float red_max_half(float x) {
  unsigned a = __float_as_uint(x), b = a;
  plane32_swap(a, b);
  return fmaxf(__uint_as_float(a), __uint_as_float(b));
}
__device__ __forceinline__ float red_sum_half(float x) {
  unsigned a = __float_as_uint(x), b = a;
  plane32_swap(a, b);
  return __uint_as_float(a) + __uint_as_float(b);
}

#define QSCALE 0.18033688011f   /* 0.125 * log2(e) */

// ---------------- GN partial stats + weight/bias convert (fused): 256 blocks ----------------
__global__ __launch_bounds__(256) void gn_stats_wcvt(
    const float* __restrict__ x, const float* __restrict__ qkv_w, const float* __restrict__ proj_w,
    const float* __restrict__ qkv_b, double2* __restrict__ partials,
    u16* __restrict__ wq, u16* __restrict__ wp, float* __restrict__ biasq)
{
  const int blk = blockIdx.x, tid = threadIdx.x;
  // weight convert: 1024 entries per block (256 blocks x 1024 = 262144)
#pragma unroll
  for (int p = 0; p < 4; ++p) {
    int idx = blk * 1024 + p * 256 + tid;
    if (idx < 196608) {
      float v = qkv_w[idx];
      if (idx < 65536) v *= QSCALE;             // q rows pre-scaled
      wq[idx] = (u16)bf16_rne(v);
    } else {
      int j = idx - 196608;
      wp[j] = (u16)bf16_rne(proj_w[j]);
    }
    if (idx < 768) {
      float bv = qkv_b[idx];
      if (idx < 256) bv *= QSCALE;
      biasq[idx] = bv;
    }
  }
  // stats partial for chunk
  const int bg = blk >> 3, chunk = blk & 7;
  const float4* base = (const float4*)(x + (size_t)bg * 131072 + (size_t)chunk * 16384);
  double s = 0.0, ss = 0.0;
  for (int idx = tid; idx < 4096; idx += 256) {
    float4 v = base[idx];
    s  += (double)v.x + (double)v.y + (double)v.z + (double)v.w;
    ss += (double)v.x * v.x + (double)v.y * v.y + (double)v.z * v.z + (double)v.w * v.w;
  }
  __shared__ double rs[256], rss[256];
  rs[tid] = s; rss[tid] = ss;
  __syncthreads();
  for (int off = 128; off > 0; off >>= 1) {
    if (tid < off) { rs[tid] += rs[tid + off]; rss[tid] += rss[tid + off]; }
    __syncthreads();
  }
  if (tid == 0) {
    double2 p; p.x = rs[0]; p.y = rss[0];
    partials[blk] = p;
  }
}

// ---------------- GN apply + transpose (self-finalizing alpha/beta) ----------------
__global__ __launch_bounds__(256) void gn_apply_t2(
    const float* __restrict__ x, const double2* __restrict__ partials,
    const float* __restrict__ gn_w, const float* __restrict__ gn_b,
    u16* __restrict__ Xt)
{
  const int b = blockIdx.z, c0 = blockIdx.y * 64, n0 = blockIdx.x * 64;
  const int tid = threadIdx.x;
  __shared__ u16 T[64 * 68];
  __shared__ float sal[64], sbe[64], smv[2], srv[2];
  if (tid < 2) {
    int bg = b * 8 + (c0 >> 5) + tid;
    double s = 0.0, ss = 0.0;
    for (int c = 0; c < 8; ++c) { double2 p = partials[bg * 8 + c]; s += p.x; ss += p.y; }
    double mean = s / 131072.0;
    double var  = ss / 131072.0 - mean * mean;
    smv[tid] = (float)mean;
    srv[tid] = (float)(1.0 / sqrt(var + 1e-5));
  }
  __syncthreads();
  if (tid < 64) {
    int g = tid >> 5;
    int ch = c0 + tid;
    float a = srv[g] * gn_w[ch];
    sal[tid] = a;
    sbe[tid] = gn_b[ch] - smv[g] * a;
  }
  __syncthreads();
  const int n4 = (tid & 15) * 4, cr = tid >> 4;
#pragma unroll
  for (int p = 0; p < 4; ++p) {
    int cl = cr + 16 * p;
    int c = c0 + cl;
    float a = sal[cl], bt = sbe[cl];
    float4 v = *(const float4*)&x[((size_t)b * CCH + c) * NPIX + n0 + n4];
    T[(n4 + 0) * 68 + cl] = (u16)bf16_rne(v.x * a + bt);
    T[(n4 + 1) * 68 + cl] = (u16)bf16_rne(v.y * a + bt);
    T[(n4 + 2) * 68 + cl] = (u16)bf16_rne(v.z * a + bt);
    T[(n4 + 3) * 68 + cl] = (u16)bf16_rne(v.w * a + bt);
  }
  __syncthreads();
#pragma unroll
  for (int it = 0; it < 2; ++it) {
    int linear = it * 256 + tid;
    int n = linear >> 3, ch = linear & 7;
    s16x8 v = *(const s16x8*)&T[n * 68 + ch * 8];
    *(s16x8*)&Xt[((size_t)b * NPIX + n0 + n) * CCH + c0 + ch * 8] = v;
  }
}

// ---------------- QKV GEMM v1 (R9-verified): D[m][n] = W[m][k] Xt[n][k] + bias ----------------
__global__ __launch_bounds__(256) void qkv_gemm_kernel(
    const u16* __restrict__ Wbf, const float* __restrict__ biasv, const u16* __restrict__ Xt,
    u16* __restrict__ Qt, u16* __restrict__ Kt, u16* __restrict__ Vb)
{
  const int nblk = blockIdx.x, m0 = blockIdx.y * 64;
  const int tid = threadIdx.x, wave = tid >> 6, lane = tid & 63;
  const int n16 = lane & 15, quad = lane >> 4;
  const int n0 = nblk * 128 + wave * 32;   // flat row (b*4096 + i)

  f32x4 acc[4][2];
#pragma unroll
  for (int a = 0; a < 4; ++a)
#pragma unroll
    for (int c = 0; c < 2; ++c) acc[a][c] = (f32x4){0.f, 0.f, 0.f, 0.f};

#pragma unroll
  for (int k0 = 0; k0 < 256; k0 += 32) {
    s16x8 af[4], bfr[2];
#pragma unroll
    for (int msub = 0; msub < 4; ++msub)
      af[msub] = *(const s16x8*)&Wbf[(size_t)(m0 + msub * 16 + n16) * 256 + k0 + quad * 8];
#pragma unroll
    for (int nsub = 0; nsub < 2; ++nsub)
      bfr[nsub] = *(const s16x8*)&Xt[(size_t)(n0 + nsub * 16 + n16) * 256 + k0 + quad * 8];
#pragma unroll
    for (int msub = 0; msub < 4; ++msub)
#pragma unroll
      for (int nsub = 0; nsub < 2; ++nsub)
        acc[msub][nsub] = __builtin_amdgcn_mfma_f32_16x16x32_bf16(af[msub], bfr[nsub], acc[msub][nsub], 0, 0, 0);
  }

  __shared__ u16 T[8704];   // qk: [n128][m 68]; v: [m64][n 136]
  if (m0 < 512) {
    // bias + pack, store transposed tile [n][m]
#pragma unroll
    for (int msub = 0; msub < 4; ++msub)
#pragma unroll
      for (int nsub = 0; nsub < 2; ++nsub) {
        float b0 = biasv[m0 + msub * 16 + quad * 4 + 0];
        float b1 = biasv[m0 + msub * 16 + quad * 4 + 1];
        float b2 = biasv[m0 + msub * 16 + quad * 4 + 2];
        float b3 = biasv[m0 + msub * 16 + quad * 4 + 3];
        uint2 w2;
        w2.x = pack2(acc[msub][nsub][0] + b0, acc[msub][nsub][1] + b1);
        w2.y = pack2(acc[msub][nsub][2] + b2, acc[msub][nsub][3] + b3);
        *(uint2*)&T[(wave * 32 + nsub * 16 + n16) * 68 + msub * 16 + quad * 4] = w2;
      }
    __syncthreads();
    u16* dst = (m0 < 256) ? Qt : Kt;
    const int coff = m0 & 255;
#pragma unroll
    for (int it = 0; it < 4; ++it) {
      int linear = it * 256 + tid;
      int n = linear >> 3, ch = linear & 7;
      s16x8 v = *(const s16x8*)&T[n * 68 + ch * 8];
      *(s16x8*)&dst[(size_t)(nblk * 128 + n) * 256 + coff + ch * 8] = v;
    }
  } else {
    // V: store [m][n] natural rows
#pragma unroll
    for (int msub = 0; msub < 4; ++msub)
#pragma unroll
      for (int nsub = 0; nsub < 2; ++nsub) {
        int ncol = wave * 32 + nsub * 16 + n16;
#pragma unroll
        for (int r = 0; r < 4; ++r) {
          int m = msub * 16 + quad * 4 + r;
          T[m * 136 + ncol] = (u16)bf16_rne(acc[msub][nsub][r] + biasv[m0 + m]);
        }
      }
    __syncthreads();
    const int b = (nblk * 128) >> 12, i0n = (nblk * 128) & 4095;
#pragma unroll
    for (int it = 0; it < 4; ++it) {
      int linear = it * 256 + tid;
      int mloc = linear >> 4, ch = linear & 15;
      s16x8 v = *(const s16x8*)&T[mloc * 136 + ch * 8];
      int c = (m0 - 512) + mloc;
      *(s16x8*)&Vb[((size_t)b * CCH + c) * NPIX + i0n + ch * 8] = v;
    }
  }
}

// ---------------- MFMA flash attention v6b (R9/R11-verified, LDS-staged) ----------------
__device__ __forceinline__ void kv_load6(
    const u16* __restrict__ Kb, const u16* __restrict__ Vg, int h, int j0, int sj, int part,
    s16x8& k0, s16x8& k1, s16x8& v0, s16x8& v1)
{
  const s16x8* kp = (const s16x8*)&Kb[(size_t)(j0 + sj) * 256 + h * 64 + part * 16];
  const s16x8* vp = (const s16x8*)&Vg[(size_t)sj * NPIX + j0 + part * 16];
  k0 = kp[0]; k1 = kp[1]; v0 = vp[0]; v1 = vp[1];
}
__device__ __forceinline__ void kv_store6(
    u16* Ksb, u16* Vsb, int sbase,
    s16x8 k0, s16x8 k1, s16x8 v0, s16x8 v1)
{
  *(s16x8*)&Ksb[sbase]       = k0;
  *(s16x8*)&Ksb[sbase + 256] = k1;
  *(s16x8*)&Vsb[sbase]       = v0;
  *(s16x8*)&Vsb[sbase + 256] = v1;
}

__device__ __forceinline__ void attn_tile6(
    const u16* Ksb, const u16* Vsb, const s16x8 qf[4], int lane,
    f32x16 ot[2], float& m_i, float& l_i)
{
  f32x16 st[2];
#pragma unroll
  for (int r = 0; r < 16; ++r) { st[0][r] = 0.f; st[1][r] = 0.f; }

  __builtin_amdgcn_s_setprio(1);
#pragma unroll
  for (int kq = 0; kq < 4; ++kq)
#pragma unroll
    for (int jsub = 0; jsub < 2; ++jsub) {
      s16x8 a = *(const s16x8*)&Ksb[(jsub * 4 + kq) * 512 + lane * 8];
      st[jsub] = __builtin_amdgcn_mfma_f32_32x32x16_bf16(a, qf[kq], st[jsub], 0, 0, 0);
    }
  __builtin_amdgcn_s_setprio(0);

  float c0 = max3f(st[0][0],  st[0][1],  st[0][2]);
  float c1 = max3f(st[0][3],  st[0][4],  st[0][5]);
  float c2 = max3f(st[0][6],  st[0][7],  st[0][8]);
  float c3 = max3f(st[0][9],  st[0][10], st[0][11]);
  float c4 = max3f(st[0][12], st[0][13], st[0][14]);
  float c5 = max3f(st[0][15], st[1][0],  st[1][1]);
  float c6 = max3f(st[1][2],  st[1][3],  st[1][4]);
  float c7 = max3f(st[1][5],  st[1][6],  st[1][7]);
  float c8 = max3f(st[1][8],  st[1][9],  st[1][10]);
  float c9 = max3f(st[1][11], st[1][12], st[1][13]);
  float d0 = max3f(c0, c1, c2);
  float d1 = max3f(c3, c4, c5);
  float d2 = max3f(c6, c7, c8);
  float d3 = max3f(c9, st[1][14], st[1][15]);
  float tm = fmaxf(fmaxf(d0, d1), fmaxf(d2, d3));
  tm = red_max_half(tm);

  if (__any(tm > m_i + 8.0f)) {
    float mn = fmaxf(m_i, tm);
    float al = __builtin_amdgcn_exp2f(m_i - mn);
    m_i = mn;
    l_i *= al;
#pragma unroll
    for (int r = 0; r < 16; ++r) { ot[0][r] *= al; ot[1][r] *= al; }
  }

#pragma unroll
  for (int f = 0; f < 2; ++f)
#pragma unroll
    for (int r = 0; r < 16; ++r)
      st[f][r] = __builtin_amdgcn_exp2f(st[f][r] - m_i);

  float s0 = (st[0][0] + st[0][1]) + (st[0][2]  + st[0][3]);
  float s1 = (st[0][4] + st[0][5]) + (st[0][6]  + st[0][7]);
  float s2 = (st[0][8] + st[0][9]) + (st[0][10] + st[0][11]);
  float s3 = (st[0][12]+ st[0][13])+ (st[0][14] + st[0][15]);
  float s4 = (st[1][0] + st[1][1]) + (st[1][2]  + st[1][3]);
  float s5 = (st[1][4] + st[1][5]) + (st[1][6]  + st[1][7]);
  float s6 = (st[1][8] + st[1][9]) + (st[1][10] + st[1][11]);
  float s7 = (st[1][12]+ st[1][13])+ (st[1][14] + st[1][15]);
  float ps = ((s0 + s1) + (s2 + s3)) + ((s4 + s5) + (s6 + s7));
  ps = red_sum_half(ps);
  l_i += ps;

  // P^T -> PV B-frags (R8-verified routing): swap(u0,u2); swap(u1,u3)
#pragma unroll
  for (int jq = 0; jq < 4; ++jq) {
    const int jsub = jq >> 1;
    const int b0 = (jq & 1) * 8;
    const int b1 = b0 + 4;
    unsigned u0 = cvtpk2(st[jsub][b0 + 0], st[jsub][b0 + 1]);
    unsigned u1 = cvtpk2(st[jsub][b0 + 2], st[jsub][b0 + 3]);
    unsigned u2 = cvtpk2(st[jsub][b1 + 0], st[jsub][b1 + 1]);
    unsigned u3 = cvtpk2(st[jsub][b1 + 2], st[jsub][b1 + 3]);
    plane32_swap(u0, u2);
    plane32_swap(u1, u3);
    union { unsigned u[4]; s16x8 v; } pu;
    pu.u[0] = u0; pu.u[1] = u1; pu.u[2] = u2; pu.u[3] = u3;
    __builtin_amdgcn_s_setprio(1);
#pragma unroll
    for (int dsub = 0; dsub < 2; ++dsub) {
      s16x8 a = *(const s16x8*)&Vsb[(dsub * 4 + jq) * 512 + lane * 8];
      ot[dsub] = __builtin_amdgcn_mfma_f32_32x32x16_bf16(a, pu.v, ot[dsub], 0, 0, 0);
    }
    __builtin_amdgcn_s_setprio(0);
  }
}

__global__ __launch_bounds__(256, 4) void attn_kernel6(
    const u16* __restrict__ Qt, const u16* __restrict__ Kt,
    const u16* __restrict__ Vb, u16* __restrict__ P0, u16* __restrict__ P1,
    float* __restrict__ mlbuf)
{
  const int b = blockIdx.z, h = blockIdx.y;
  const int xb = blockIdx.x;
  const int half = xb >> 5, iblk = xb & 31;
  const int tid = threadIdx.x;
  const int wave = tid >> 6, lane = tid & 63;
  const int i0w = iblk * 128 + wave * 32;

  __shared__ u16 Ks[2][4096];
  __shared__ u16 Vs[2][4096];

  const u16* Qb = Qt + (size_t)b * NPIX * 256;
  const u16* Kb = Kt + (size_t)b * NPIX * 256;
  const u16* Vg = Vb + ((size_t)b * CCH + h * 64) * NPIX;

  s16x8 qf[4];
#pragma unroll
  for (int kq = 0; kq < 4; ++kq)
    qf[kq] = *(const s16x8*)&Qb[(size_t)(i0w + (lane & 31)) * 256 + h * 64 + kq * 16 + (lane >> 5) * 8];

  f32x16 ot[2];
#pragma unroll
  for (int r = 0; r < 16; ++r) { ot[0][r] = 0.f; ot[1][r] = 0.f; }
  float m_i = -1e30f;
  float l_i = 0.f;

  const int sj = tid >> 2;
  const int part = tid & 3;
  const int sbase = ((sj >> 5) * 4 + part) * 512 + (sj & 31) * 8;
  const int jbase = half * 2048;

  s16x8 k0, k1, v0, v1;

  kv_load6(Kb, Vg, h, jbase, sj, part, k0, k1, v0, v1);
  kv_store6(Ks[0], Vs[0], sbase, k0, k1, v0, v1);
  __syncthreads();

#pragma unroll 1
  for (int t = 0; t < 30; t += 2) {
    kv_load6(Kb, Vg, h, jbase + (t + 1) * 64, sj, part, k0, k1, v0, v1);
    attn_tile6(Ks[0], Vs[0], qf, lane, ot, m_i, l_i);
    kv_store6(Ks[1], Vs[1], sbase, k0, k1, v0, v1);
    __syncthreads();
    kv_load6(Kb, Vg, h, jbase + (t + 2) * 64, sj, part, k0, k1, v0, v1);
    attn_tile6(Ks[1], Vs[1], qf, lane, ot, m_i, l_i);
    kv_store6(Ks[0], Vs[0], sbase, k0, k1, v0, v1);
    __syncthreads();
  }
  kv_load6(Kb, Vg, h, jbase + 31 * 64, sj, part, k0, k1, v0, v1);
  attn_tile6(Ks[0], Vs[0], qf, lane, ot, m_i, l_i);
  kv_store6(Ks[1], Vs[1], sbase, k0, k1, v0, v1);
  __syncthreads();
  attn_tile6(Ks[1], Vs[1], qf, lane, ot, m_i, l_i);

  float rl = 1.0f / l_i;
  u16* dst = (half == 0) ? P0 : P1;
  const size_t rowbase = (size_t)((size_t)b * NPIX + i0w + (lane & 31)) * 256 + h * 64 + (lane >> 5) * 4;
#pragma unroll
  for (int dsub = 0; dsub < 2; ++dsub)
#pragma unroll
    for (int q = 0; q < 4; ++q) {
      uint2 w2;
      w2.x = cvtpk2(ot[dsub][4 * q + 0] * rl, ot[dsub][4 * q + 1] * rl);
      w2.y = cvtpk2(ot[dsub][4 * q + 2] * rl, ot[dsub][4 * q + 3] * rl);
      *(uint2*)&dst[rowbase + dsub * 32 + q * 8] = w2;
    }
  if (lane < 32) {
    int idx = half * 65536 + b * 16384 + h * 4096 + i0w + lane;
    float2 ml; ml.x = m_i; ml.y = l_i;
    *(float2*)&mlbuf[idx * 2] = ml;
  }
}

// ---------------- Proj GEMM v1 + fused split-KV combine ----------------
__global__ __launch_bounds__(256) void proj_gemm_cmb(
    const u16* __restrict__ Wp, const float* __restrict__ proj_b,
    const u16* __restrict__ P0, const u16* __restrict__ P1, const float* __restrict__ mlbuf,
    const float* __restrict__ x, float* __restrict__ out)
{
  const int nblk = blockIdx.x, m0 = blockIdx.y * 64;
  const int tid = threadIdx.x, wave = tid >> 6, lane = tid & 63;
  const int n16 = lane & 15, quad = lane >> 4;
  const int n0 = nblk * 128 + wave * 32;

  // combine weights for this thread's 2 rows x 4 heads
  float w0h[2][4], w1h[2][4];
#pragma unroll
  for (int ns = 0; ns < 2; ++ns) {
    int row = n0 + ns * 16 + n16;
    int bb = row >> 12, ii = row & 4095;
#pragma unroll
    for (int h = 0; h < 4; ++h) {
      int idx = bb * 16384 + h * 4096 + ii;
      float2 ml0 = *(const float2*)&mlbuf[(size_t)idx * 2];
      float2 ml1 = *(const float2*)&mlbuf[(size_t)(65536 + idx) * 2];
      float m = fmaxf(ml0.x, ml1.x);
      float cc0 = ml0.y * __builtin_amdgcn_exp2f(ml0.x - m);
      float cc1 = ml1.y * __builtin_amdgcn_exp2f(ml1.x - m);
      float rn = 1.0f / (cc0 + cc1);
      w0h[ns][h] = cc0 * rn;
      w1h[ns][h] = cc1 * rn;
    }
  }

  f32x4 acc[4][2];
#pragma unroll
  for (int a = 0; a < 4; ++a)
#pragma unroll
    for (int c = 0; c < 2; ++c) acc[a][c] = (f32x4){0.f, 0.f, 0.f, 0.f};

#pragma unroll
  for (int k0 = 0; k0 < 256; k0 += 32) {
    const int h = k0 >> 6;            // compile-time per unrolled iter
    s16x8 af[4], bfr[2];
#pragma unroll
    for (int msub = 0; msub < 4; ++msub)
      af[msub] = *(const s16x8*)&Wp[(size_t)(m0 + msub * 16 + n16) * 256 + k0 + quad * 8];
#pragma unroll
    for (int nsub = 0; nsub < 2; ++nsub) {
      int row = n0 + nsub * 16 + n16;
      size_t off = (size_t)row * 256 + k0 + quad * 8;
      s16x8 a = *(const s16x8*)&P0[off];
      s16x8 c = *(const s16x8*)&P1[off];
      float w0 = w0h[nsub][h], w1 = w1h[nsub][h];
      union { unsigned u[4]; s16x8 v; } o;
#pragma unroll
      for (int e = 0; e < 4; ++e) {
        float lo = w0 * bf16_to_f32((unsigned short)a[2 * e])     + w1 * bf16_to_f32((unsigned short)c[2 * e]);
        float hi = w0 * bf16_to_f32((unsigned short)a[2 * e + 1]) + w1 * bf16_to_f32((unsigned short)c[2 * e + 1]);
        o.u[e] = cvtpk2(lo, hi);
      }
      bfr[nsub] = o.v;
    }
#pragma unroll
    for (int msub = 0; msub < 4; ++msub)
#pragma unroll
      for (int nsub = 0; nsub < 2; ++nsub)
        acc[msub][nsub] = __builtin_amdgcn_mfma_f32_16x16x32_bf16(af[msub], bfr[nsub], acc[msub][nsub], 0, 0, 0);
  }

  __shared__ float T[64 * 132];
#pragma unroll
  for (int msub = 0; msub < 4; ++msub)
#pragma unroll
    for (int nsub = 0; nsub < 2; ++nsub) {
      int ncol = wave * 32 + nsub * 16 + n16;
#pragma unroll
      for (int r = 0; r < 4; ++r) {
        int m = msub * 16 + quad * 4 + r;
        T[m * 132 + ncol] = acc[msub][nsub][r];
      }
    }
  __syncthreads();
  const int b = (nblk * 128) >> 12, i0n = (nblk * 128) & 4095;
#pragma unroll
  for (int it = 0; it < 8; ++it) {
    int linear = it * 256 + tid;
    int m = linear >> 5, ch = linear & 31;
    f32x4 v = *(const f32x4*)&T[m * 132 + ch * 4];
    float bs = proj_b[m0 + m];
    size_t g = ((size_t)b * CCH + m0 + m) * NPIX + i0n + ch * 4;
    float4 rv = *(const float4*)&x[g];
    float4 o;
    o.x = v[0] + bs + rv.x; o.y = v[1] + bs + rv.y;
    o.z = v[2] + bs + rv.z; o.w = v[3] + bs + rv.w;
    *(float4*)&out[g] = o;
  }
}

extern "C" void kernel_launch(void* const* d_in, const int* in_sizes, int n_in,
                              void* d_out, int out_size, void* d_ws, size_t ws_size,
                              hipStream_t stream)
{
  const float* x      = (const float*)d_in[0];
  const float* gn_w   = (const float*)d_in[1];
  const float* gn_b   = (const float*)d_in[2];
  const float* qkv_w  = (const float*)d_in[3];
  const float* qkv_b  = (const float*)d_in[4];
  const float* proj_w = (const float*)d_in[5];
  const float* proj_b = (const float*)d_in[6];
  float* out = (float*)d_out;

  float* ws    = (float*)d_ws;
  float* biasq = ws + 2048;                // 768
  double2* partials = (double2*)(ws + 2816); // 256 double2 -> ends 3840
  u16*   wq    = (u16*)(ws + 4096);        // 196608 shorts
  u16*   wp    = (u16*)(ws + 102400);      // 65536 shorts
  u16*   Xt    = (u16*)(ws + 135168);      // 4*4096*256 shorts = 2097152 floats
  u16*   Qt    = (u16*)(ws + 2232320);
  u16*   Kt    = (u16*)(ws + 4329472);
  u16*   Vb    = (u16*)(ws + 6426624);
  u16*   Ot    = (u16*)(ws + 8523776);     // ends 10620928 (holds P1)
  float* mlbuf = ws + 10620928;            // 2*65536*2 floats -> ends 10883072 (~43.5 MB)

  // P0 (half-0 partial O) overlays Xt (dead after qkv_gemm); P1 = Ot region.
  u16* P0 = Xt;

  gn_stats_wcvt<<<256, 256, 0, stream>>>(x, qkv_w, proj_w, qkv_b, partials, wq, wp, biasq);
  gn_apply_t2<<<dim3(64, 4, 4), 256, 0, stream>>>(x, partials, gn_w, gn_b, Xt);
  qkv_gemm_kernel<<<dim3(128, 12), 256, 0, stream>>>(wq, biasq, Xt, Qt, Kt, Vb);
  attn_kernel6<<<dim3(64, 4, 4), 256, 0, stream>>>(Qt, Kt, Vb, P0, Ot, mlbuf);
  proj_gemm_cmb<<<dim3(128, 4), 256, 0, stream>>>(wp, proj_b, P0, Ot, mlbuf, x, out);
}

// Round 18
// 237.983 us; speedup vs baseline: 1.4736x; 1.0142x over previous
//
#include <hip/hip_runtime.h>
#include <math.h>

#define NPIX 4096
#define CCH 256

typedef __attribute__((ext_vector_type(4))) float f32x4;
typedef __attribute__((ext_vector_type(16))) float f32x16;
typedef __attribute__((ext_vector_type(8))) short s16x8;
typedef unsigned short u16;

__device__ __forceinline__ short bf16_rne(float x) {
  union { float f; unsigned u; } c; c.f = x;
  unsigned r = c.u + 0x7FFF + ((c.u >> 16) & 1);
  return (short)(r >> 16);
}
__device__ __forceinline__ unsigned cvtpk2(float lo, float hi) {
  unsigned r;
  asm("v_cvt_pk_bf16_f32 %0, %1, %2" : "=v"(r) : "v"(lo), "v"(hi));
  return r;
}
__device__ __forceinline__ unsigned pack2(float a, float b) {
  return cvtpk2(a, b);
}
__device__ __forceinline__ float max3f(float a, float b, float c) {
  float d;
  asm("v_max3_f32 %0, %1, %2, %3" : "=v"(d) : "v"(a), "v"(b), "v"(c));
  return d;
}
__device__ __forceinline__ float bf16_to_f32(unsigned short v) {
  return __uint_as_float(((unsigned)v) << 16);
}

// permlane32_swap via builtin (compiler-managed hazards — R2 lesson).
// TRUE semantics (R7 lesson): swap(a,b) -> a' = [a.lo, b.lo], b' = [a.hi, b.hi]
__device__ __forceinline__ void plane32_swap(unsigned& a, unsigned& b) {
#if __has_builtin(__builtin_amdgcn_permlane32_swap)
  auto r = __builtin_amdgcn_permlane32_swap(a, b, false, false);
  a = r[0]; b = r[1];
#else
  asm("s_nop 2\n\tv_permlane32_swap_b32 %0, %1\n\ts_nop 2" : "+v"(a), "+v"(b));
#endif
}
// cross-half (lane l <-> l+32) reductions, VALU pipe only
__device__ __forceinline__ float red_max_half(float x) {
  unsigned a = __float_as_uint(x), b = a;
  plane32_swap(a, b);
  return fmaxf(__uint_as_float(a), __uint_as_float(b));
}
__device__ __forceinline__ float red_sum_half(float x) {
  unsigned a = __float_as_uint(x), b = a;
  plane32_swap(a, b);
  return __uint_as_float(a) + __uint_as_float(b);
}

#define QSCALE 0.18033688011f   /* 0.125 * log2(e) */

// ---------------- GN partial stats + weight/bias convert (fused): 256 blocks ----------------
// R17: per-thread accumulation in fp32 (fp64 VALU is slow on gfx950); block
// reduce stays double. Error ~1e-6 in var — invisible vs bf16 quantization.
__global__ __launch_bounds__(256) void gn_stats_wcvt(
    const float* __restrict__ x, const float* __restrict__ qkv_w, const float* __restrict__ proj_w,
    const float* __restrict__ qkv_b, double2* __restrict__ partials,
    u16* __restrict__ wq, u16* __restrict__ wp, float* __restrict__ biasq)
{
  const int blk = blockIdx.x, tid = threadIdx.x;
  // weight convert: 1024 entries per block (256 blocks x 1024 = 262144)
#pragma unroll
  for (int p = 0; p < 4; ++p) {
    int idx = blk * 1024 + p * 256 + tid;
    if (idx < 196608) {
      float v = qkv_w[idx];
      if (idx < 65536) v *= QSCALE;             // q rows pre-scaled
      wq[idx] = (u16)bf16_rne(v);
    } else {
      int j = idx - 196608;
      wp[j] = (u16)bf16_rne(proj_w[j]);
    }
    if (idx < 768) {
      float bv = qkv_b[idx];
      if (idx < 256) bv *= QSCALE;
      biasq[idx] = bv;
    }
  }
  // stats partial for chunk (fp32 per-thread accumulation)
  const int bg = blk >> 3, chunk = blk & 7;
  const float4* base = (const float4*)(x + (size_t)bg * 131072 + (size_t)chunk * 16384);
  float s = 0.f, ss = 0.f;
  for (int idx = tid; idx < 4096; idx += 256) {
    float4 v = base[idx];
    s  += (v.x + v.y) + (v.z + v.w);
    ss += (v.x * v.x + v.y * v.y) + (v.z * v.z + v.w * v.w);
  }
  __shared__ double rs[256], rss[256];
  rs[tid] = (double)s; rss[tid] = (double)ss;
  __syncthreads();
  for (int off = 128; off > 0; off >>= 1) {
    if (tid < off) { rs[tid] += rs[tid + off]; rss[tid] += rss[tid + off]; }
    __syncthreads();
  }
  if (tid == 0) {
    double2 p; p.x = rs[0]; p.y = rss[0];
    partials[blk] = p;
  }
}

// ---------------- GN apply + transpose (self-finalizing alpha/beta) ----------------
__global__ __launch_bounds__(256) void gn_apply_t2(
    const float* __restrict__ x, const double2* __restrict__ partials,
    const float* __restrict__ gn_w, const float* __restrict__ gn_b,
    u16* __restrict__ Xt)
{
  const int b = blockIdx.z, c0 = blockIdx.y * 64, n0 = blockIdx.x * 64;
  const int tid = threadIdx.x;
  __shared__ u16 T[64 * 68];
  __shared__ float sal[64], sbe[64], smv[2], srv[2];
  if (tid < 2) {
    int bg = b * 8 + (c0 >> 5) + tid;
    double s = 0.0, ss = 0.0;
    for (int c = 0; c < 8; ++c) { double2 p = partials[bg * 8 + c]; s += p.x; ss += p.y; }
    double mean = s / 131072.0;
    double var  = ss / 131072.0 - mean * mean;
    smv[tid] = (float)mean;
    srv[tid] = (float)(1.0 / sqrt(var + 1e-5));
  }
  __syncthreads();
  if (tid < 64) {
    int g = tid >> 5;
    int ch = c0 + tid;
    float a = srv[g] * gn_w[ch];
    sal[tid] = a;
    sbe[tid] = gn_b[ch] - smv[g] * a;
  }
  __syncthreads();
  const int n4 = (tid & 15) * 4, cr = tid >> 4;
#pragma unroll
  for (int p = 0; p < 4; ++p) {
    int cl = cr + 16 * p;
    int c = c0 + cl;
    float a = sal[cl], bt = sbe[cl];
    float4 v = *(const float4*)&x[((size_t)b * CCH + c) * NPIX + n0 + n4];
    T[(n4 + 0) * 68 + cl] = (u16)bf16_rne(v.x * a + bt);
    T[(n4 + 1) * 68 + cl] = (u16)bf16_rne(v.y * a + bt);
    T[(n4 + 2) * 68 + cl] = (u16)bf16_rne(v.z * a + bt);
    T[(n4 + 3) * 68 + cl] = (u16)bf16_rne(v.w * a + bt);
  }
  __syncthreads();
#pragma unroll
  for (int it = 0; it < 2; ++it) {
    int linear = it * 256 + tid;
    int n = linear >> 3, ch = linear & 7;
    s16x8 v = *(const s16x8*)&T[n * 68 + ch * 8];
    *(s16x8*)&Xt[((size_t)b * NPIX + n0 + n) * CCH + c0 + ch * 8] = v;
  }
}

// ---------------- QKV GEMM v1 (R9-verified): D[m][n] = W[m][k] Xt[n][k] + bias ----------------
__global__ __launch_bounds__(256) void qkv_gemm_kernel(
    const u16* __restrict__ Wbf, const float* __restrict__ biasv, const u16* __restrict__ Xt,
    u16* __restrict__ Qt, u16* __restrict__ Kt, u16* __restrict__ Vb)
{
  const int nblk = blockIdx.x, m0 = blockIdx.y * 64;
  const int tid = threadIdx.x, wave = tid >> 6, lane = tid & 63;
  const int n16 = lane & 15, quad = lane >> 4;
  const int n0 = nblk * 128 + wave * 32;   // flat row (b*4096 + i)

  f32x4 acc[4][2];
#pragma unroll
  for (int a = 0; a < 4; ++a)
#pragma unroll
    for (int c = 0; c < 2; ++c) acc[a][c] = (f32x4){0.f, 0.f, 0.f, 0.f};

#pragma unroll
  for (int k0 = 0; k0 < 256; k0 += 32) {
    s16x8 af[4], bfr[2];
#pragma unroll
    for (int msub = 0; msub < 4; ++msub)
      af[msub] = *(const s16x8*)&Wbf[(size_t)(m0 + msub * 16 + n16) * 256 + k0 + quad * 8];
#pragma unroll
    for (int nsub = 0; nsub < 2; ++nsub)
      bfr[nsub] = *(const s16x8*)&Xt[(size_t)(n0 + nsub * 16 + n16) * 256 + k0 + quad * 8];
#pragma unroll
    for (int msub = 0; msub < 4; ++msub)
#pragma unroll
      for (int nsub = 0; nsub < 2; ++nsub)
        acc[msub][nsub] = __builtin_amdgcn_mfma_f32_16x16x32_bf16(af[msub], bfr[nsub], acc[msub][nsub], 0, 0, 0);
  }

  __shared__ u16 T[8704];   // qk: [n128][m 68]; v: [m64][n 136]
  if (m0 < 512) {
    // bias + pack, store transposed tile [n][m]
#pragma unroll
    for (int msub = 0; msub < 4; ++msub)
#pragma unroll
      for (int nsub = 0; nsub < 2; ++nsub) {
        float b0 = biasv[m0 + msub * 16 + quad * 4 + 0];
        float b1 = biasv[m0 + msub * 16 + quad * 4 + 1];
        float b2 = biasv[m0 + msub * 16 + quad * 4 + 2];
        float b3 = biasv[m0 + msub * 16 + quad * 4 + 3];
        uint2 w2;
        w2.x = pack2(acc[msub][nsub][0] + b0, acc[msub][nsub][1] + b1);
        w2.y = pack2(acc[msub][nsub][2] + b2, acc[msub][nsub][3] + b3);
        *(uint2*)&T[(wave * 32 + nsub * 16 + n16) * 68 + msub * 16 + quad * 4] = w2;
      }
    __syncthreads();
    u16* dst = (m0 < 256) ? Qt : Kt;
    const int coff = m0 & 255;
#pragma unroll
    for (int it = 0; it < 4; ++it) {
      int linear = it * 256 + tid;
      int n = linear >> 3, ch = linear & 7;
      s16x8 v = *(const s16x8*)&T[n * 68 + ch * 8];
      *(s16x8*)&dst[(size_t)(nblk * 128 + n) * 256 + coff + ch * 8] = v;
    }
  } else {
    // V: store [m][n] natural rows
#pragma unroll
    for (int msub = 0; msub < 4; ++msub)
#pragma unroll
      for (int nsub = 0; nsub < 2; ++nsub) {
        int ncol = wave * 32 + nsub * 16 + n16;
#pragma unroll
        for (int r = 0; r < 4; ++r) {
          int m = msub * 16 + quad * 4 + r;
          T[m * 136 + ncol] = (u16)bf16_rne(acc[msub][nsub][r] + biasv[m0 + m]);
        }
      }
    __syncthreads();
    const int b = (nblk * 128) >> 12, i0n = (nblk * 128) & 4095;
#pragma unroll
    for (int it = 0; it < 4; ++it) {
      int linear = it * 256 + tid;
      int mloc = linear >> 4, ch = linear & 15;
      s16x8 v = *(const s16x8*)&T[mloc * 136 + ch * 8];
      int c = (m0 - 512) + mloc;
      *(s16x8*)&Vb[((size_t)b * CCH + c) * NPIX + i0n + ch * 8] = v;
    }
  }
}

// ---------------- MFMA flash attention v6b (R9/R11-verified, LDS-staged) ----------------
__device__ __forceinline__ void kv_load6(
    const u16* __restrict__ Kb, const u16* __restrict__ Vg, int h, int j0, int sj, int part,
    s16x8& k0, s16x8& k1, s16x8& v0, s16x8& v1)
{
  const s16x8* kp = (const s16x8*)&Kb[(size_t)(j0 + sj) * 256 + h * 64 + part * 16];
  const s16x8* vp = (const s16x8*)&Vg[(size_t)sj * NPIX + j0 + part * 16];
  k0 = kp[0]; k1 = kp[1]; v0 = vp[0]; v1 = vp[1];
}
__device__ __forceinline__ void kv_store6(
    u16* Ksb, u16* Vsb, int sbase,
    s16x8 k0, s16x8 k1, s16x8 v0, s16x8 v1)
{
  *(s16x8*)&Ksb[sbase]       = k0;
  *(s16x8*)&Ksb[sbase + 256] = k1;
  *(s16x8*)&Vsb[sbase]       = v0;
  *(s16x8*)&Vsb[sbase + 256] = v1;
}

__device__ __forceinline__ void attn_tile6(
    const u16* Ksb, const u16* Vsb, const s16x8 qf[4], int lane,
    f32x16 ot[2], float& m_i, float& l_i)
{
  f32x16 st[2];
#pragma unroll
  for (int r = 0; r < 16; ++r) { st[0][r] = 0.f; st[1][r] = 0.f; }

  __builtin_amdgcn_s_setprio(1);
#pragma unroll
  for (int kq = 0; kq < 4; ++kq)
#pragma unroll
    for (int jsub = 0; jsub < 2; ++jsub) {
      s16x8 a = *(const s16x8*)&Ksb[(jsub * 4 + kq) * 512 + lane * 8];
      st[jsub] = __builtin_amdgcn_mfma_f32_32x32x16_bf16(a, qf[kq], st[jsub], 0, 0, 0);
    }
  __builtin_amdgcn_s_setprio(0);

  float c0 = max3f(st[0][0],  st[0][1],  st[0][2]);
  float c1 = max3f(st[0][3],  st[0][4],  st[0][5]);
  float c2 = max3f(st[0][6],  st[0][7],  st[0][8]);
  float c3 = max3f(st[0][9],  st[0][10], st[0][11]);
  float c4 = max3f(st[0][12], st[0][13], st[0][14]);
  float c5 = max3f(st[0][15], st[1][0],  st[1][1]);
  float c6 = max3f(st[1][2],  st[1][3],  st[1][4]);
  float c7 = max3f(st[1][5],  st[1][6],  st[1][7]);
  float c8 = max3f(st[1][8],  st[1][9],  st[1][10]);
  float c9 = max3f(st[1][11], st[1][12], st[1][13]);
  float d0 = max3f(c0, c1, c2);
  float d1 = max3f(c3, c4, c5);
  float d2 = max3f(c6, c7, c8);
  float d3 = max3f(c9, st[1][14], st[1][15]);
  float tm = fmaxf(fmaxf(d0, d1), fmaxf(d2, d3));
  tm = red_max_half(tm);

  if (__any(tm > m_i + 8.0f)) {
    float mn = fmaxf(m_i, tm);
    float al = __builtin_amdgcn_exp2f(m_i - mn);
    m_i = mn;
    l_i *= al;
#pragma unroll
    for (int r = 0; r < 16; ++r) { ot[0][r] *= al; ot[1][r] *= al; }
  }

#pragma unroll
  for (int f = 0; f < 2; ++f)
#pragma unroll
    for (int r = 0; r < 16; ++r)
      st[f][r] = __builtin_amdgcn_exp2f(st[f][r] - m_i);

  float s0 = (st[0][0] + st[0][1]) + (st[0][2]  + st[0][3]);
  float s1 = (st[0][4] + st[0][5]) + (st[0][6]  + st[0][7]);
  float s2 = (st[0][8] + st[0][9]) + (st[0][10] + st[0][11]);
  float s3 = (st[0][12]+ st[0][13])+ (st[0][14] + st[0][15]);
  float s4 = (st[1][0] + st[1][1]) + (st[1][2]  + st[1][3]);
  float s5 = (st[1][4] + st[1][5]) + (st[1][6]  + st[1][7]);
  float s6 = (st[1][8] + st[1][9]) + (st[1][10] + st[1][11]);
  float s7 = (st[1][12]+ st[1][13])+ (st[1][14] + st[1][15]);
  float ps = ((s0 + s1) + (s2 + s3)) + ((s4 + s5) + (s6 + s7));
  ps = red_sum_half(ps);
  l_i += ps;

  // P^T -> PV B-frags (R8-verified routing): swap(u0,u2); swap(u1,u3)
#pragma unroll
  for (int jq = 0; jq < 4; ++jq) {
    const int jsub = jq >> 1;
    const int b0 = (jq & 1) * 8;
    const int b1 = b0 + 4;
    unsigned u0 = cvtpk2(st[jsub][b0 + 0], st[jsub][b0 + 1]);
    unsigned u1 = cvtpk2(st[jsub][b0 + 2], st[jsub][b0 + 3]);
    unsigned u2 = cvtpk2(st[jsub][b1 + 0], st[jsub][b1 + 1]);
    unsigned u3 = cvtpk2(st[jsub][b1 + 2], st[jsub][b1 + 3]);
    plane32_swap(u0, u2);
    plane32_swap(u1, u3);
    union { unsigned u[4]; s16x8 v; } pu;
    pu.u[0] = u0; pu.u[1] = u1; pu.u[2] = u2; pu.u[3] = u3;
    __builtin_amdgcn_s_setprio(1);
#pragma unroll
    for (int dsub = 0; dsub < 2; ++dsub) {
      s16x8 a = *(const s16x8*)&Vsb[(dsub * 4 + jq) * 512 + lane * 8];
      ot[dsub] = __builtin_amdgcn_mfma_f32_32x32x16_bf16(a, pu.v, ot[dsub], 0, 0, 0);
    }
    __builtin_amdgcn_s_setprio(0);
  }
}

__global__ __launch_bounds__(256, 4) void attn_kernel6(
    const u16* __restrict__ Qt, const u16* __restrict__ Kt,
    const u16* __restrict__ Vb, u16* __restrict__ P0, u16* __restrict__ P1,
    float* __restrict__ mlbuf)
{
  const int b = blockIdx.z, h = blockIdx.y;
  const int xb = blockIdx.x;
  const int half = xb >> 5, iblk = xb & 31;
  const int tid = threadIdx.x;
  const int wave = tid >> 6, lane = tid & 63;
  const int i0w = iblk * 128 + wave * 32;

  __shared__ u16 Ks[2][4096];
  __shared__ u16 Vs[2][4096];

  const u16* Qb = Qt + (size_t)b * NPIX * 256;
  const u16* Kb = Kt + (size_t)b * NPIX * 256;
  const u16* Vg = Vb + ((size_t)b * CCH + h * 64) * NPIX;

  s16x8 qf[4];
#pragma unroll
  for (int kq = 0; kq < 4; ++kq)
    qf[kq] = *(const s16x8*)&Qb[(size_t)(i0w + (lane & 31)) * 256 + h * 64 + kq * 16 + (lane >> 5) * 8];

  f32x16 ot[2];
#pragma unroll
  for (int r = 0; r < 16; ++r) { ot[0][r] = 0.f; ot[1][r] = 0.f; }
  float m_i = -1e30f;
  float l_i = 0.f;

  const int sj = tid >> 2;
  const int part = tid & 3;
  const int sbase = ((sj >> 5) * 4 + part) * 512 + (sj & 31) * 8;
  const int jbase = half * 2048;

  s16x8 k0, k1, v0, v1;

  kv_load6(Kb, Vg, h, jbase, sj, part, k0, k1, v0, v1);
  kv_store6(Ks[0], Vs[0], sbase, k0, k1, v0, v1);
  __syncthreads();

#pragma unroll 1
  for (int t = 0; t < 30; t += 2) {
    kv_load6(Kb, Vg, h, jbase + (t + 1) * 64, sj, part, k0, k1, v0, v1);
    attn_tile6(Ks[0], Vs[0], qf, lane, ot, m_i, l_i);
    kv_store6(Ks[1], Vs[1], sbase, k0, k1, v0, v1);
    __syncthreads();
    kv_load6(Kb, Vg, h, jbase + (t + 2) * 64, sj, part, k0, k1, v0, v1);
    attn_tile6(Ks[1], Vs[1], qf, lane, ot, m_i, l_i);
    kv_store6(Ks[0], Vs[0], sbase, k0, k1, v0, v1);
    __syncthreads();
  }
  kv_load6(Kb, Vg, h, jbase + 31 * 64, sj, part, k0, k1, v0, v1);
  attn_tile6(Ks[0], Vs[0], qf, lane, ot, m_i, l_i);
  kv_store6(Ks[1], Vs[1], sbase, k0, k1, v0, v1);
  __syncthreads();
  attn_tile6(Ks[1], Vs[1], qf, lane, ot, m_i, l_i);

  float rl = 1.0f / l_i;
  u16* dst = (half == 0) ? P0 : P1;
  const size_t rowbase = (size_t)((size_t)b * NPIX + i0w + (lane & 31)) * 256 + h * 64 + (lane >> 5) * 4;
#pragma unroll
  for (int dsub = 0; dsub < 2; ++dsub)
#pragma unroll
    for (int q = 0; q < 4; ++q) {
      uint2 w2;
      w2.x = cvtpk2(ot[dsub][4 * q + 0] * rl, ot[dsub][4 * q + 1] * rl);
      w2.y = cvtpk2(ot[dsub][4 * q + 2] * rl, ot[dsub][4 * q + 3] * rl);
      *(uint2*)&dst[rowbase + dsub * 32 + q * 8] = w2;
    }
  if (lane < 32) {
    int idx = half * 65536 + b * 16384 + h * 4096 + i0w + lane;
    float2 ml; ml.x = m_i; ml.y = l_i;
    *(float2*)&mlbuf[idx * 2] = ml;
  }
}

// ---------------- Proj GEMM v1 + fused split-KV combine ----------------
__global__ __launch_bounds__(256) void proj_gemm_cmb(
    const u16* __restrict__ Wp, const float* __restrict__ proj_b,
    const u16* __restrict__ P0, const u16* __restrict__ P1, const float* __restrict__ mlbuf,
    const float* __restrict__ x, float* __restrict__ out)
{
  const int nblk = blockIdx.x, m0 = blockIdx.y * 64;
  const int tid = threadIdx.x, wave = tid >> 6, lane = tid & 63;
  const int n16 = lane & 15, quad = lane >> 4;
  const int n0 = nblk * 128 + wave * 32;

  // combine weights for this thread's 2 rows x 4 heads
  float w0h[2][4], w1h[2][4];
#pragma unroll
  for (int ns = 0; ns < 2; ++ns) {
    int row = n0 + ns * 16 + n16;
    int bb = row >> 12, ii = row & 4095;
#pragma unroll
    for (int h = 0; h < 4; ++h) {
      int idx = bb * 16384 + h * 4096 + ii;
      float2 ml0 = *(const float2*)&mlbuf[(size_t)idx * 2];
      float2 ml1 = *(const float2*)&mlbuf[(size_t)(65536 + idx) * 2];
      float m = fmaxf(ml0.x, ml1.x);
      float cc0 = ml0.y * __builtin_amdgcn_exp2f(ml0.x - m);
      float cc1 = ml1.y * __builtin_amdgcn_exp2f(ml1.x - m);
      float rn = 1.0f / (cc0 + cc1);
      w0h[ns][h] = cc0 * rn;
      w1h[ns][h] = cc1 * rn;
    }
  }

  f32x4 acc[4][2];
#pragma unroll
  for (int a = 0; a < 4; ++a)
#pragma unroll
    for (int c = 0; c < 2; ++c) acc[a][c] = (f32x4){0.f, 0.f, 0.f, 0.f};

#pragma unroll
  for (int k0 = 0; k0 < 256; k0 += 32) {
    const int h = k0 >> 6;            // compile-time per unrolled iter
    s16x8 af[4], bfr[2];
#pragma unroll
    for (int msub = 0; msub < 4; ++msub)
      af[msub] = *(const s16x8*)&Wp[(size_t)(m0 + msub * 16 + n16) * 256 + k0 + quad * 8];
#pragma unroll
    for (int nsub = 0; nsub < 2; ++nsub) {
      int row = n0 + nsub * 16 + n16;
      size_t off = (size_t)row * 256 + k0 + quad * 8;
      s16x8 a = *(const s16x8*)&P0[off];
      s16x8 c = *(const s16x8*)&P1[off];
      float w0 = w0h[nsub][h], w1 = w1h[nsub][h];
      union { unsigned u[4]; s16x8 v; } o;
#pragma unroll
      for (int e = 0; e < 4; ++e) {
        float lo = w0 * bf16_to_f32((unsigned short)a[2 * e])     + w1 * bf16_to_f32((unsigned short)c[2 * e]);
        float hi = w0 * bf16_to_f32((unsigned short)a[2 * e + 1]) + w1 * bf16_to_f32((unsigned short)c[2 * e + 1]);
        o.u[e] = cvtpk2(lo, hi);
      }
      bfr[nsub] = o.v;
    }
#pragma unroll
    for (int msub = 0; msub < 4; ++msub)
#pragma unroll
      for (int nsub = 0; nsub < 2; ++nsub)
        acc[msub][nsub] = __builtin_amdgcn_mfma_f32_16x16x32_bf16(af[msub], bfr[nsub], acc[msub][nsub], 0, 0, 0);
  }

  __shared__ float T[64 * 132];
#pragma unroll
  for (int msub = 0; msub < 4; ++msub)
#pragma unroll
    for (int nsub = 0; nsub < 2; ++nsub) {
      int ncol = wave * 32 + nsub * 16 + n16;
#pragma unroll
      for (int r = 0; r < 4; ++r) {
        int m = msub * 16 + quad * 4 + r;
        T[m * 132 + ncol] = acc[msub][nsub][r];
      }
    }
  __syncthreads();
  const int b = (nblk * 128) >> 12, i0n = (nblk * 128) & 4095;
#pragma unroll
  for (int it = 0; it < 8; ++it) {
    int linear = it * 256 + tid;
    int m = linear >> 5, ch = linear & 31;
    f32x4 v = *(const f32x4*)&T[m * 132 + ch * 4];
    float bs = proj_b[m0 + m];
    size_t g = ((size_t)b * CCH + m0 + m) * NPIX + i0n + ch * 4;
    float4 rv = *(const float4*)&x[g];
    float4 o;
    o.x = v[0] + bs + rv.x; o.y = v[1] + bs + rv.y;
    o.z = v[2] + bs + rv.z; o.w = v[3] + bs + rv.w;
    *(float4*)&out[g] = o;
  }
}

extern "C" void kernel_launch(void* const* d_in, const int* in_sizes, int n_in,
                              void* d_out, int out_size, void* d_ws, size_t ws_size,
                              hipStream_t stream)
{
  const float* x      = (const float*)d_in[0];
  const float* gn_w   = (const float*)d_in[1];
  const float* gn_b   = (const float*)d_in[2];
  const float* qkv_w  = (const float*)d_in[3];
  const float* qkv_b  = (const float*)d_in[4];
  const float* proj_w = (const float*)d_in[5];
  const float* proj_b = (const float*)d_in[6];
  float* out = (float*)d_out;

  float* ws    = (float*)d_ws;
  float* biasq = ws + 2048;                // 768
  double2* partials = (double2*)(ws + 2816); // 256 double2 -> ends 3840
  u16*   wq    = (u16*)(ws + 4096);        // 196608 shorts
  u16*   wp    = (u16*)(ws + 102400);      // 65536 shorts
  u16*   Xt    = (u16*)(ws + 135168);      // 4*4096*256 shorts = 2097152 floats
  u16*   Qt    = (u16*)(ws + 2232320);
  u16*   Kt    = (u16*)(ws + 4329472);
  u16*   Vb    = (u16*)(ws + 6426624);
  u16*   Ot    = (u16*)(ws + 8523776);     // ends 10620928 (holds P1)
  float* mlbuf = ws + 10620928;            // 2*65536*2 floats -> ends 10883072 (~43.5 MB)

  // P0 (half-0 partial O) overlays Xt (dead after qkv_gemm); P1 = Ot region.
  u16* P0 = Xt;

  gn_stats_wcvt<<<256, 256, 0, stream>>>(x, qkv_w, proj_w, qkv_b, partials, wq, wp, biasq);
  gn_apply_t2<<<dim3(64, 4, 4), 256, 0, stream>>>(x, partials, gn_w, gn_b, Xt);
  qkv_gemm_kernel<<<dim3(128, 12), 256, 0, stream>>>(wq, biasq, Xt, Qt, Kt, Vb);
  attn_kernel6<<<dim3(64, 4, 4), 256, 0, stream>>>(Qt, Kt, Vb, P0, Ot, mlbuf);
  proj_gemm_cmb<<<dim3(128, 4), 256, 0, stream>>>(wp, proj_b, P0, Ot, mlbuf, x, out);
}